// Round 14
// baseline (68.858 us; speedup 1.0000x reference)
//
#include <hip/hip_runtime.h>
#include <hip/hip_bf16.h>

#define EPS 1e-5f
#define SLOPE 0.01f

typedef __attribute__((ext_vector_type(8))) short bfrag8;   // 8 bf16 (4 VGPRs)
typedef __attribute__((ext_vector_type(4))) float f32x4;

// ---- workspace byte offsets ----
#define WS_SIM_OFF   0u          // [1024][16] f32
#define WS_S_OFF     65536u      // [1024][16] f32
#define WS_WVS_OFF   131072u     // [2048][16] f32, transposed [c][n]
#define WS_BVS_OFF   262144u     // [16] f32
#define WS_OUT_OFF   262208u     // [1024][2048] f32 (q cols 0-1023, k cols 1024-2047)
#define WS_BIMG_OFF  8650816u    // bf16 B image, FRAGMENT-ordered: [nt32][wc2][kt32][ks2][ni2][lane64]x16B = 8,388,608 B

// round-to-nearest-even fp32 -> bf16
__device__ __forceinline__ unsigned short f2bf(float f) {
    union { float f; unsigned int u; } x; x.f = f;
    unsigned int r = (x.u + 0x7FFFu + ((x.u >> 16) & 1u)) >> 16;
    return (unsigned short)r;
}
__device__ __forceinline__ uint4 pack8(const float4& a, const float4& b) {
    uint4 r;
    r.x = (unsigned)f2bf(a.x) | ((unsigned)f2bf(a.y) << 16);
    r.y = (unsigned)f2bf(a.z) | ((unsigned)f2bf(a.w) << 16);
    r.z = (unsigned)f2bf(b.x) | ((unsigned)f2bf(b.y) << 16);
    r.w = (unsigned)f2bf(b.z) | ((unsigned)f2bf(b.w) << 16);
    return r;
}
// packed fp32->bf16 RNE (single VALU op; m214v22-verified pattern)
__device__ __forceinline__ unsigned cvtpk(float lo, float hi) {
    unsigned r;
    asm("v_cvt_pk_bf16_f32 %0, %1, %2" : "=v"(r) : "v"(lo), "v"(hi));
    return r;
}

// ---------------- kernel 0: prep — fragment-ordered bf16 B image + WvS + bvS ----------------
// B granule: lane l holds cols (l&15), k = ks*32 + (l>>4)*8 .. +8 (m92-verified frag layout).
// Granule index bits MUST match gemm read strides: [nt:14+][wc:13][kt:8-12][ks:7][ni:6][l:0-5]
// (round-12 bug: kt/wc/nt were decoded one bit high, scrambling the image).
#define PREP_B2   524288                    // 32nt*2wc*32kt*2ks*2ni*64l
#define PREP_WVSE (PREP_B2 + 32768)
#define PREP_END  (PREP_WVSE + 16)

__global__ __launch_bounds__(256) void prep_kernel(
        const float* __restrict__ Wq, const float* __restrict__ Wkv,
        const float* __restrict__ bkv, unsigned char* __restrict__ ws) {
    int gid = blockIdx.x * 256 + threadIdx.x;
    if (gid < PREP_B2) {
        int l   = gid & 63;
        int ni  = (gid >> 6) & 1;
        int ks  = (gid >> 7) & 1;
        int kt  = (gid >> 8) & 31;
        int wcg = (gid >> 13) & 1;
        int nt  = gid >> 14;                  // 0..31
        int col = nt * 64 + wcg * 32 + ni * 16 + (l & 15);
        int k   = kt * 64 + ks * 32 + (l >> 4) * 8;
        const float* wrow;
        if (col < 1024) wrow = Wq + (size_t)col * 2048;
        else {
            int c2 = col - 1024;
            wrow = Wkv + (size_t)(((c2 >> 6) << 7) + (c2 & 63)) * 2048;
        }
        float4 v0 = *(const float4*)(wrow + k);
        float4 v1 = *(const float4*)(wrow + k + 4);
        *(uint4*)(ws + WS_BIMG_OFF + (size_t)gid * 16) = pack8(v0, v1);
    } else if (gid < PREP_WVSE) {
        int g2 = gid - PREP_B2;
        int n = g2 >> 11, c = g2 & 2047;
        const float* base = Wkv + (size_t)(n * 128 + 64) * 2048 + c;
        float s = 0.f;
        #pragma unroll 8
        for (int d = 0; d < 64; ++d) s += base[(size_t)d * 2048];
        ((float*)(ws + WS_WVS_OFF))[c * 16 + n] = s;
    } else if (gid < PREP_END) {
        int n = gid - PREP_WVSE;
        float b = 0.f;
        #pragma unroll
        for (int d = 0; d < 64; ++d) b += bkv[n * 128 + 64 + d];
        ((float*)(ws + WS_BVS_OFF))[n] = b;
    }
}

// ---------------- kernel 1: projection GEMM — B streamed from L2 (frag image), A reg->LDS ----------------
// grid (x=nt 32, y=mt 16) = 512 blocks (2/CU), 256 thr = 4 waves, wave C = 32x32.
// NO vmcnt at barriers: raw s_barrier + lgkmcnt(0) only -> compiler-pipelined global
// loads (B frags + next A fp32) stay in flight across barriers. A: fp32 -> cvt_pk ->
// swizzled ds_write into 16 KB double buffer (T2 involution, r8-r10-verified).
__global__ __launch_bounds__(256) void gemm_qk_kernel(
        const float* __restrict__ qin, const float* __restrict__ kvin,
        unsigned char* __restrict__ ws) {
    __shared__ alignas(16) unsigned short LA[2][4096];   // 2 x 8 KB, 64 rows x 128 B swizzled

    const int t = threadIdx.x;
    const int w = t >> 6, l = t & 63;
    const int nt = blockIdx.x, mt = blockIdx.y;
    const int wr = w >> 1, wc = w & 1;
    const int lrow = l & 15, lhi = l >> 4;
    const int m0 = mt * 64;

    // A staging map: thread t -> row t>>2, slot pair (2q, 2q+1), q = t&3
    const int arow = t >> 2, aq4 = t & 3;
    const int gk0 = aq4 * 2, gk1 = gk0 + 1;
    const float* aSrc = ((nt >= 16) ? kvin : qin) + (size_t)(m0 + arow) * 2048;
    const int adst0 = arow * 128 + ((gk0 ^ (arow & 7)) << 4);   // byte offsets
    const int adst1 = arow * 128 + ((gk1 ^ (arow & 7)) << 4);
    unsigned char* lds = (unsigned char*)&LA[0][0];

    // B fragment pointer for this wave (L2-resident panel; lane-coalesced)
    const unsigned char* bP = ws + WS_BIMG_OFF
        + (size_t)(nt * 2 + wc) * 131072 + (size_t)l * 16;

    float* Out = (float*)(ws + WS_OUT_OFF);

    // swizzled ds_read byte offsets (slot = (ks*4+lhi) ^ (row&7))
    int offA[2][2];
    #pragma unroll
    for (int ks = 0; ks < 2; ++ks)
        #pragma unroll
        for (int i = 0; i < 2; ++i) {
            int r = wr * 32 + i * 16 + lrow;
            offA[ks][i] = r * 128 + (((ks * 4 + lhi) ^ (r & 7)) << 4);
        }

    f32x4 acc00 = (f32x4)0.f, acc01 = (f32x4)0.f, acc10 = (f32x4)0.f, acc11 = (f32x4)0.f;

#define LOAD_A(kt_, S) do {                                                   \
    S[0] = *(const float4*)(aSrc + (kt_) * 64 + gk0 * 8);                     \
    S[1] = *(const float4*)(aSrc + (kt_) * 64 + gk0 * 8 + 4);                 \
    S[2] = *(const float4*)(aSrc + (kt_) * 64 + gk1 * 8);                     \
    S[3] = *(const float4*)(aSrc + (kt_) * 64 + gk1 * 8 + 4); } while (0)

#define WRITE_A(S, buf_) do {                                                 \
    uint4 _u0, _u1;                                                           \
    _u0.x = cvtpk(S[0].x, S[0].y); _u0.y = cvtpk(S[0].z, S[0].w);             \
    _u0.z = cvtpk(S[1].x, S[1].y); _u0.w = cvtpk(S[1].z, S[1].w);             \
    _u1.x = cvtpk(S[2].x, S[2].y); _u1.y = cvtpk(S[2].z, S[2].w);             \
    _u1.z = cvtpk(S[3].x, S[3].y); _u1.w = cvtpk(S[3].z, S[3].w);             \
    *(uint4*)(lds + (buf_) * 8192 + adst0) = _u0;                             \
    *(uint4*)(lds + (buf_) * 8192 + adst1) = _u1; } while (0)

#define BARRIER() do {                                                        \
    asm volatile("s_waitcnt lgkmcnt(0)" ::: "memory");                        \
    __builtin_amdgcn_sched_barrier(0);                                        \
    __builtin_amdgcn_s_barrier();                                             \
    __builtin_amdgcn_sched_barrier(0); } while (0)

#define COMPUTE(kt_, buf_) do {                                               \
    const char* _la = (const char*)lds + (buf_) * 8192;                       \
    const unsigned char* _bp = bP + (size_t)(kt_) * 4096;                     \
    _Pragma("unroll")                                                         \
    for (int _ks = 0; _ks < 2; ++_ks) {                                       \
        bfrag8 _fa0 = *(const bfrag8*)(_la + offA[_ks][0]);                   \
        bfrag8 _fa1 = *(const bfrag8*)(_la + offA[_ks][1]);                   \
        bfrag8 _fb0 = *(const bfrag8*)(_bp + _ks * 2048);                     \
        bfrag8 _fb1 = *(const bfrag8*)(_bp + _ks * 2048 + 1024);              \
        acc00 = __builtin_amdgcn_mfma_f32_16x16x32_bf16(_fa0, _fb0, acc00, 0, 0, 0); \
        acc01 = __builtin_amdgcn_mfma_f32_16x16x32_bf16(_fa0, _fb1, acc01, 0, 0, 0); \
        acc10 = __builtin_amdgcn_mfma_f32_16x16x32_bf16(_fa1, _fb0, acc10, 0, 0, 0); \
        acc11 = __builtin_amdgcn_mfma_f32_16x16x32_bf16(_fa1, _fb1, acc11, 0, 0, 0); \
    } } while (0)

    float4 E[4], O[4];   // literal-indexed only (rule 20 safe)

    // ---- prologue ----
    LOAD_A(0, E);
    WRITE_A(E, 0);
    LOAD_A(1, O);
    BARRIER();

    // ---- main loop: 16 x unroll-2, A write one buffer ahead, no vmcnt drains ----
    for (int j = 0; j < 16; ++j) {
        const int kt = 2 * j;
        if (j < 15) LOAD_A(kt + 2, E);
        COMPUTE(kt, 0);
        WRITE_A(O, 1);                    // A(kt+1) -> buf1 (readers passed last barrier)
        BARRIER();
        if (j < 15) LOAD_A(kt + 3, O);
        COMPUTE(kt + 1, 1);
        if (j < 15) {
            WRITE_A(E, 0);                // A(kt+2) -> buf0
            BARRIER();
        }
    }
#undef LOAD_A
#undef WRITE_A
#undef BARRIER
#undef COMPUTE

    // epilogue: store C fp32 (bias applied exactly in sim_s)
    f32x4 acc[2][2] = {{acc00, acc01}, {acc10, acc11}};
    #pragma unroll
    for (int mi = 0; mi < 2; ++mi)
        #pragma unroll
        for (int ni = 0; ni < 2; ++ni) {
            int col = nt * 64 + wc * 32 + ni * 16 + lrow;
            #pragma unroll
            for (int r = 0; r < 4; ++r) {
                int row = m0 + wr * 32 + mi * 16 + lhi * 4 + r;
                Out[(size_t)row * 2048 + col] = acc[mi][ni][r];
            }
        }
}

// ---------------- kernel 2: sim[b,h] = (q+bq)·(k+bk) ; S[b][n] = kv·WvS + bvS ----------------
__global__ __launch_bounds__(256) void sim_s_kernel(
        const float* __restrict__ bq, const float* __restrict__ bkv,
        const float* __restrict__ kvin, unsigned char* __restrict__ ws) {
    int b = blockIdx.x, t = threadIdx.x;
    int w = t >> 6, l = t & 63;
    {
        const float* orow = (const float*)(ws + WS_OUT_OFF) + (size_t)b * 2048;
        float* sim = (float*)(ws + WS_SIM_OFF);
        #pragma unroll
        for (int hh = 0; hh < 4; ++hh) {
            int h = w * 4 + hh;
            float qv = orow[h * 64 + l]        + bq[h * 64 + l];
            float kv = orow[1024 + h * 64 + l] + bkv[h * 128 + l];
            float p = qv * kv;
            p += __shfl_xor(p, 1);  p += __shfl_xor(p, 2);
            p += __shfl_xor(p, 4);  p += __shfl_xor(p, 8);
            p += __shfl_xor(p, 16); p += __shfl_xor(p, 32);
            if (l == 0) sim[b * 16 + h] = p;
        }
    }
    __shared__ float SW[4][16];
    int n = t & 15, g = t >> 4;
    const float* kvrow = kvin + (size_t)b * 2048;
    const float* wv = (const float*)(ws + WS_WVS_OFF);
    float p = 0.f;
    #pragma unroll 4
    for (int tt = 0; tt < 128; ++tt) {
        int c = g + (tt << 4);
        p = fmaf(kvrow[c], wv[c * 16 + n], p);
    }
    p += __shfl_xor(p, 16);
    p += __shfl_xor(p, 32);
    if (l < 16) SW[w][n] = p;
    __syncthreads();
    if (t < 16) {
        float sv = SW[0][t] + SW[1][t] + SW[2][t] + SW[3][t]
                 + ((const float*)(ws + WS_BVS_OFF))[t];
        ((float*)(ws + WS_S_OFF))[b * 16 + t] = sv;
    }
}

// ---------------- kernel 3: softmax, A-reduce, pooled, leaky, batchnorm, output ----------------
__global__ __launch_bounds__(1024) void final_kernel(
        const float* __restrict__ bn_w, const float* __restrict__ bn_b,
        const float* __restrict__ Wo, const float* __restrict__ bo,
        const unsigned char* __restrict__ ws, float* __restrict__ out) {
    int t = threadIdx.x;
    int w = t >> 6;
    int l = t & 63;
    __shared__ float Aw[16][16];
    __shared__ float Af[4][16];
    __shared__ float SWs[16][8];
    __shared__ float FS[8];
    __shared__ float sc[4], sh[4];

    float a16[16];
    {
        const float* srow = (const float*)(ws + WS_SIM_OFF) + (size_t)t * 16;
        float4 v0 = *(const float4*)(srow + 0);
        float4 v1 = *(const float4*)(srow + 4);
        float4 v2 = *(const float4*)(srow + 8);
        float4 v3 = *(const float4*)(srow + 12);
        a16[0]=v0.x; a16[1]=v0.y; a16[2]=v0.z; a16[3]=v0.w;
        a16[4]=v1.x; a16[5]=v1.y; a16[6]=v1.z; a16[7]=v1.w;
        a16[8]=v2.x; a16[9]=v2.y; a16[10]=v2.z; a16[11]=v2.w;
        a16[12]=v3.x; a16[13]=v3.y; a16[14]=v3.z; a16[15]=v3.w;
        float m = a16[0];
        #pragma unroll
        for (int n = 1; n < 16; ++n) m = fmaxf(m, a16[n]);
        float den = 0.f;
        #pragma unroll
        for (int n = 0; n < 16; ++n) { a16[n] = expf(a16[n] - m); den += a16[n]; }
        float inv = 1.f / den;
        #pragma unroll
        for (int n = 0; n < 16; ++n) a16[n] *= inv;
    }
    #pragma unroll
    for (int n = 0; n < 16; ++n) {
        float p = a16[n];
        p += __shfl_xor(p, 1);  p += __shfl_xor(p, 2);
        p += __shfl_xor(p, 4);  p += __shfl_xor(p, 8);
        p += __shfl_xor(p, 16); p += __shfl_xor(p, 32);
        a16[n] = p;
    }
    if (l == 0) {
        #pragma unroll
        for (int n = 0; n < 16; ++n) Aw[w][n] = a16[n];
    }
    __syncthreads();
    if (t < 64) {
        int f = t >> 4, n = t & 15;
        Af[f][n] = Aw[4*f][n] + Aw[4*f+1][n] + Aw[4*f+2][n] + Aw[4*f+3][n];
    }
    __syncthreads();

    float sv[16];
    {
        const float* srow = (const float*)(ws + WS_S_OFF) + (size_t)t * 16;
        float4 v0 = *(const float4*)(srow + 0);
        float4 v1 = *(const float4*)(srow + 4);
        float4 v2 = *(const float4*)(srow + 8);
        float4 v3 = *(const float4*)(srow + 12);
        sv[0]=v0.x; sv[1]=v0.y; sv[2]=v0.z; sv[3]=v0.w;
        sv[4]=v1.x; sv[5]=v1.y; sv[6]=v1.z; sv[7]=v1.w;
        sv[8]=v2.x; sv[9]=v2.y; sv[10]=v2.z; sv[11]=v2.w;
        sv[12]=v3.x; sv[13]=v3.y; sv[14]=v3.z; sv[15]=v3.w;
    }
    float x[4];
    #pragma unroll
    for (int f = 0; f < 4; ++f) {
        float p = 0.f;
        #pragma unroll
        for (int n = 0; n < 16; ++n) p = fmaf(Af[f][n], sv[n], p);
        p *= (1.f / 16384.f);
        x[f] = (p >= 0.f) ? p : SLOPE * p;
    }

    float st[8];
    #pragma unroll
    for (int f = 0; f < 4; ++f) { st[f] = x[f]; st[4 + f] = x[f] * x[f]; }
    #pragma unroll
    for (int j = 0; j < 8; ++j) {
        float p = st[j];
        p += __shfl_xor(p, 1);  p += __shfl_xor(p, 2);
        p += __shfl_xor(p, 4);  p += __shfl_xor(p, 8);
        p += __shfl_xor(p, 16); p += __shfl_xor(p, 32);
        st[j] = p;
    }
    if (l == 0) {
        #pragma unroll
        for (int j = 0; j < 8; ++j) SWs[w][j] = st[j];
    }
    __syncthreads();
    if (t < 8) {
        float p = 0.f;
        #pragma unroll
        for (int ww = 0; ww < 16; ++ww) p += SWs[ww][t];
        FS[t] = p;
    }
    __syncthreads();
    if (t < 4) {
        float mean = FS[t] * (1.f / 1024.f);
        float var  = FS[4 + t] * (1.f / 1024.f) - mean * mean;
        float s = bn_w[t] / sqrtf(var + EPS);
        sc[t] = s;
        sh[t] = bn_b[t] - mean * s;
    }
    __syncthreads();

    float o0 = bo[0], o1 = bo[1];
    #pragma unroll
    for (int f = 0; f < 4; ++f) {
        float xh = x[f] * sc[f] + sh[f];
        o0 = fmaf(xh, Wo[f], o0);
        o1 = fmaf(xh, Wo[4 + f], o1);
    }
    *(float2*)(out + (size_t)t * 2) = make_float2(o0, o1);
}

// ---------------- launch ----------------
extern "C" void kernel_launch(void* const* d_in, const int* in_sizes, int n_in,
                              void* d_out, int out_size, void* d_ws, size_t ws_size,
                              hipStream_t stream) {
    const float* q_input  = (const float*)d_in[0];
    const float* kv_input = (const float*)d_in[1];
    const float* Wq   = (const float*)d_in[2];
    const float* bq   = (const float*)d_in[3];
    const float* Wkv  = (const float*)d_in[4];
    const float* bkv  = (const float*)d_in[5];
    const float* bn_w = (const float*)d_in[6];
    const float* bn_b = (const float*)d_in[7];
    const float* Wo   = (const float*)d_in[8];
    const float* bo   = (const float*)d_in[9];
    float* out = (float*)d_out;
    unsigned char* ws = (unsigned char*)d_ws;

    hipLaunchKernelGGL(prep_kernel, dim3((PREP_END + 255) / 256), dim3(256), 0, stream,
                       Wq, Wkv, bkv, ws);
    hipLaunchKernelGGL(gemm_qk_kernel, dim3(32, 16), dim3(256), 0, stream,
                       q_input, kv_input, ws);
    hipLaunchKernelGGL(sim_s_kernel, dim3(1024), dim3(256), 0, stream,
                       bq, bkv, kv_input, ws);
    hipLaunchKernelGGL(final_kernel, dim3(1), dim3(1024), 0, stream,
                       bn_w, bn_b, Wo, bo, ws, out);
}

// Round 16
// 68.276 us; speedup vs baseline: 1.0085x; 1.0085x over previous
//
#include <hip/hip_runtime.h>
#include <hip/hip_bf16.h>

#define EPS 1e-5f
#define SLOPE 0.01f

typedef __attribute__((ext_vector_type(8))) short bfrag8;   // 8 bf16 (4 VGPRs)
typedef __attribute__((ext_vector_type(4))) float f32x4;

// ---- workspace byte offsets ----
#define WS_SIM_OFF   0u          // [1024][16] f32
#define WS_S_OFF     65536u      // [1024][16] f32
#define WS_WVS_OFF   131072u     // [2048][16] f32, transposed [c][n]
#define WS_BVS_OFF   262144u     // [16] f32
#define WS_OUT_OFF   262208u     // [1024][2048] f32 (q cols 0-1023, k cols 1024-2047)
#define WS_BIMG_OFF  8650816u    // bf16 B image, FRAGMENT-ordered: [nt32][wc2][kt32][ks2][ni2][lane64]x16B = 8,388,608 B

// round-to-nearest-even fp32 -> bf16
__device__ __forceinline__ unsigned short f2bf(float f) {
    union { float f; unsigned int u; } x; x.f = f;
    unsigned int r = (x.u + 0x7FFFu + ((x.u >> 16) & 1u)) >> 16;
    return (unsigned short)r;
}
__device__ __forceinline__ uint4 pack8(const float4& a, const float4& b) {
    uint4 r;
    r.x = (unsigned)f2bf(a.x) | ((unsigned)f2bf(a.y) << 16);
    r.y = (unsigned)f2bf(a.z) | ((unsigned)f2bf(a.w) << 16);
    r.z = (unsigned)f2bf(b.x) | ((unsigned)f2bf(b.y) << 16);
    r.w = (unsigned)f2bf(b.z) | ((unsigned)f2bf(b.w) << 16);
    return r;
}
// packed fp32->bf16 RNE (single VALU op)
__device__ __forceinline__ unsigned cvtpk(float lo, float hi) {
    unsigned r;
    asm("v_cvt_pk_bf16_f32 %0, %1, %2" : "=v"(r) : "v"(lo), "v"(hi));
    return r;
}

// ---------------- kernel 0: prep — fragment-ordered bf16 B image + WvS + bvS ----------------
// Granule bits match gemm read strides: [nt:14+][wc:13][kt:8-12][ks:7][ni:6][l:0-5].
#define PREP_B2   524288
#define PREP_WVSE (PREP_B2 + 32768)
#define PREP_END  (PREP_WVSE + 16)

__global__ __launch_bounds__(256) void prep_kernel(
        const float* __restrict__ Wq, const float* __restrict__ Wkv,
        const float* __restrict__ bkv, unsigned char* __restrict__ ws) {
    int gid = blockIdx.x * 256 + threadIdx.x;
    if (gid < PREP_B2) {
        int l   = gid & 63;
        int ni  = (gid >> 6) & 1;
        int ks  = (gid >> 7) & 1;
        int kt  = (gid >> 8) & 31;
        int wcg = (gid >> 13) & 1;
        int nt  = gid >> 14;                  // 0..31
        int col = nt * 64 + wcg * 32 + ni * 16 + (l & 15);
        int k   = kt * 64 + ks * 32 + (l >> 4) * 8;
        const float* wrow;
        if (col < 1024) wrow = Wq + (size_t)col * 2048;
        else {
            int c2 = col - 1024;
            wrow = Wkv + (size_t)(((c2 >> 6) << 7) + (c2 & 63)) * 2048;
        }
        float4 v0 = *(const float4*)(wrow + k);
        float4 v1 = *(const float4*)(wrow + k + 4);
        *(uint4*)(ws + WS_BIMG_OFF + (size_t)gid * 16) = pack8(v0, v1);
    } else if (gid < PREP_WVSE) {
        int g2 = gid - PREP_B2;
        int n = g2 >> 11, c = g2 & 2047;
        const float* base = Wkv + (size_t)(n * 128 + 64) * 2048 + c;
        float s = 0.f;
        #pragma unroll 8
        for (int d = 0; d < 64; ++d) s += base[(size_t)d * 2048];
        ((float*)(ws + WS_WVS_OFF))[c * 16 + n] = s;
    } else if (gid < PREP_END) {
        int n = gid - PREP_WVSE;
        float b = 0.f;
        #pragma unroll
        for (int d = 0; d < 64; ++d) b += bkv[n * 128 + 64 + d];
        ((float*)(ws + WS_BVS_OFF))[n] = b;
    }
}

// ---------------- kernel 1: projection GEMM — B reg-prefetched from L2, A reg->LDS ----------------
// grid (x=nt 32, y=mt 16) = 512 blocks (2/CU), 256 thr = 4 waves, wave C = 32x32.
// Round-14 lesson: B loads inside COMPUTE were pinned behind memory-clobber barriers
// -> full L2 latency exposed per iter (MfmaUtil 7%). Fix: SOURCE-ORDER register
// prefetch — LOAD_B(kt+1) into named reg set issued before COMPUTE(kt);
// sched_barrier pins removed (MFMA ordering protected by data deps on
// compiler-visible ds_reads, which can't cross the clobber barrier).
__global__ __launch_bounds__(256) void gemm_qk_kernel(
        const float* __restrict__ qin, const float* __restrict__ kvin,
        unsigned char* __restrict__ ws) {
    __shared__ alignas(16) unsigned short LA[2][4096];   // 2 x 8 KB, 64 rows x 128 B swizzled

    const int t = threadIdx.x;
    const int w = t >> 6, l = t & 63;
    const int nt = blockIdx.x, mt = blockIdx.y;
    const int wr = w >> 1, wc = w & 1;
    const int lrow = l & 15, lhi = l >> 4;
    const int m0 = mt * 64;

    // A staging map: thread t -> row t>>2, slot pair (2q, 2q+1), q = t&3
    const int arow = t >> 2, aq4 = t & 3;
    const int gk0 = aq4 * 2, gk1 = gk0 + 1;
    const float* aSrc = ((nt >= 16) ? kvin : qin) + (size_t)(m0 + arow) * 2048;
    const int adst0 = arow * 128 + ((gk0 ^ (arow & 7)) << 4);   // byte offsets
    const int adst1 = arow * 128 + ((gk1 ^ (arow & 7)) << 4);
    unsigned char* lds = (unsigned char*)&LA[0][0];

    // B fragment pointer for this wave (L2-resident panel; lane-coalesced)
    const unsigned char* bP = ws + WS_BIMG_OFF
        + (size_t)(nt * 2 + wc) * 131072 + (size_t)l * 16;

    float* Out = (float*)(ws + WS_OUT_OFF);

    // swizzled ds_read byte offsets (slot = (ks*4+lhi) ^ (row&7))
    int offA[2][2];
    #pragma unroll
    for (int ks = 0; ks < 2; ++ks)
        #pragma unroll
        for (int i = 0; i < 2; ++i) {
            int r = wr * 32 + i * 16 + lrow;
            offA[ks][i] = r * 128 + (((ks * 4 + lhi) ^ (r & 7)) << 4);
        }

    f32x4 acc00 = (f32x4)0.f, acc01 = (f32x4)0.f, acc10 = (f32x4)0.f, acc11 = (f32x4)0.f;

#define LOAD_A(kt_, S) do {                                                   \
    S[0] = *(const float4*)(aSrc + (kt_) * 64 + gk0 * 8);                     \
    S[1] = *(const float4*)(aSrc + (kt_) * 64 + gk0 * 8 + 4);                 \
    S[2] = *(const float4*)(aSrc + (kt_) * 64 + gk1 * 8);                     \
    S[3] = *(const float4*)(aSrc + (kt_) * 64 + gk1 * 8 + 4); } while (0)

#define WRITE_A(S, buf_) do {                                                 \
    uint4 _u0, _u1;                                                           \
    _u0.x = cvtpk(S[0].x, S[0].y); _u0.y = cvtpk(S[0].z, S[0].w);             \
    _u0.z = cvtpk(S[1].x, S[1].y); _u0.w = cvtpk(S[1].z, S[1].w);             \
    _u1.x = cvtpk(S[2].x, S[2].y); _u1.y = cvtpk(S[2].z, S[2].w);             \
    _u1.z = cvtpk(S[3].x, S[3].y); _u1.w = cvtpk(S[3].z, S[3].w);             \
    *(uint4*)(lds + (buf_) * 8192 + adst0) = _u0;                             \
    *(uint4*)(lds + (buf_) * 8192 + adst1) = _u1; } while (0)

// B reg prefetch: 4 bfrag8 per k-tile (ks0/ni0, ks0/ni1, ks1/ni0, ks1/ni1)
#define LOAD_B(kt_, S) do {                                                   \
    const unsigned char* _bp = bP + (size_t)(kt_) * 4096;                     \
    S[0] = *(const bfrag8*)(_bp);                                             \
    S[1] = *(const bfrag8*)(_bp + 1024);                                      \
    S[2] = *(const bfrag8*)(_bp + 2048);                                      \
    S[3] = *(const bfrag8*)(_bp + 3072); } while (0)

#define BARRIER() do {                                                        \
    asm volatile("s_waitcnt lgkmcnt(0)" ::: "memory");                        \
    __builtin_amdgcn_s_barrier(); } while (0)

#define COMPUTE_R(buf_, S) do {                                               \
    const char* _la = (const char*)lds + (buf_) * 8192;                       \
    bfrag8 _fa00 = *(const bfrag8*)(_la + offA[0][0]);                        \
    bfrag8 _fa01 = *(const bfrag8*)(_la + offA[0][1]);                        \
    bfrag8 _fa10 = *(const bfrag8*)(_la + offA[1][0]);                        \
    bfrag8 _fa11 = *(const bfrag8*)(_la + offA[1][1]);                        \
    acc00 = __builtin_amdgcn_mfma_f32_16x16x32_bf16(_fa00, S[0], acc00, 0, 0, 0); \
    acc01 = __builtin_amdgcn_mfma_f32_16x16x32_bf16(_fa00, S[1], acc01, 0, 0, 0); \
    acc10 = __builtin_amdgcn_mfma_f32_16x16x32_bf16(_fa01, S[0], acc10, 0, 0, 0); \
    acc11 = __builtin_amdgcn_mfma_f32_16x16x32_bf16(_fa01, S[1], acc11, 0, 0, 0); \
    acc00 = __builtin_amdgcn_mfma_f32_16x16x32_bf16(_fa10, S[2], acc00, 0, 0, 0); \
    acc01 = __builtin_amdgcn_mfma_f32_16x16x32_bf16(_fa10, S[3], acc01, 0, 0, 0); \
    acc10 = __builtin_amdgcn_mfma_f32_16x16x32_bf16(_fa11, S[2], acc10, 0, 0, 0); \
    acc11 = __builtin_amdgcn_mfma_f32_16x16x32_bf16(_fa11, S[3], acc11, 0, 0, 0); \
} while (0)

    float4 E[4], O[4];     // A fp32 staging reg sets (literal-indexed)
    bfrag8 X[4], Y[4];     // B fragment reg sets (literal-indexed)

    // ---- prologue ----
    LOAD_A(0, E);
    WRITE_A(E, 0);
    LOAD_A(1, O);
    LOAD_B(0, X);
    BARRIER();

    // ---- main loop: 16 x unroll-2; B prefetched 1 tile ahead in SOURCE order ----
    for (int j = 0; j < 16; ++j) {
        const int kt = 2 * j;
        if (j < 15) LOAD_A(kt + 2, E);
        LOAD_B(kt + 1, Y);                // issue->use distance: COMPUTE+write+barrier
        COMPUTE_R(0, X);                  // k-tile kt
        WRITE_A(O, 1);                    // A(kt+1) -> buf1
        BARRIER();
        if (j < 15) LOAD_A(kt + 3, O);
        if (j < 15) LOAD_B(kt + 2, X);
        COMPUTE_R(1, Y);                  // k-tile kt+1
        if (j < 15) {
            WRITE_A(E, 0);                // A(kt+2) -> buf0
            BARRIER();
        }
    }
#undef LOAD_A
#undef WRITE_A
#undef LOAD_B
#undef BARRIER
#undef COMPUTE_R

    // epilogue: store C fp32 (bias applied exactly in sim_s)
    f32x4 acc[2][2] = {{acc00, acc01}, {acc10, acc11}};
    #pragma unroll
    for (int mi = 0; mi < 2; ++mi)
        #pragma unroll
        for (int ni = 0; ni < 2; ++ni) {
            int col = nt * 64 + wc * 32 + ni * 16 + lrow;
            #pragma unroll
            for (int r = 0; r < 4; ++r) {
                int row = m0 + wr * 32 + mi * 16 + lhi * 4 + r;
                Out[(size_t)row * 2048 + col] = acc[mi][ni][r];
            }
        }
}

// ---------------- kernel 2: sim[b,h] = (q+bq)·(k+bk) ; S[b][n] = kv·WvS + bvS ----------------
__global__ __launch_bounds__(256) void sim_s_kernel(
        const float* __restrict__ bq, const float* __restrict__ bkv,
        const float* __restrict__ kvin, unsigned char* __restrict__ ws) {
    int b = blockIdx.x, t = threadIdx.x;
    int w = t >> 6, l = t & 63;
    {
        const float* orow = (const float*)(ws + WS_OUT_OFF) + (size_t)b * 2048;
        float* sim = (float*)(ws + WS_SIM_OFF);
        #pragma unroll
        for (int hh = 0; hh < 4; ++hh) {
            int h = w * 4 + hh;
            float qv = orow[h * 64 + l]        + bq[h * 64 + l];
            float kv = orow[1024 + h * 64 + l] + bkv[h * 128 + l];
            float p = qv * kv;
            p += __shfl_xor(p, 1);  p += __shfl_xor(p, 2);
            p += __shfl_xor(p, 4);  p += __shfl_xor(p, 8);
            p += __shfl_xor(p, 16); p += __shfl_xor(p, 32);
            if (l == 0) sim[b * 16 + h] = p;
        }
    }
    __shared__ float SW[4][16];
    int n = t & 15, g = t >> 4;
    const float* kvrow = kvin + (size_t)b * 2048;
    const float* wv = (const float*)(ws + WS_WVS_OFF);
    float p = 0.f;
    #pragma unroll 4
    for (int tt = 0; tt < 128; ++tt) {
        int c = g + (tt << 4);
        p = fmaf(kvrow[c], wv[c * 16 + n], p);
    }
    p += __shfl_xor(p, 16);
    p += __shfl_xor(p, 32);
    if (l < 16) SW[w][n] = p;
    __syncthreads();
    if (t < 16) {
        float sv = SW[0][t] + SW[1][t] + SW[2][t] + SW[3][t]
                 + ((const float*)(ws + WS_BVS_OFF))[t];
        ((float*)(ws + WS_S_OFF))[b * 16 + t] = sv;
    }
}

// ---------------- kernel 3: softmax, A-reduce, pooled, leaky, batchnorm, output ----------------
__global__ __launch_bounds__(1024) void final_kernel(
        const float* __restrict__ bn_w, const float* __restrict__ bn_b,
        const float* __restrict__ Wo, const float* __restrict__ bo,
        const unsigned char* __restrict__ ws, float* __restrict__ out) {
    int t = threadIdx.x;
    int w = t >> 6;
    int l = t & 63;
    __shared__ float Aw[16][16];
    __shared__ float Af[4][16];
    __shared__ float SWs[16][8];
    __shared__ float FS[8];
    __shared__ float sc[4], sh[4];

    float a16[16];
    {
        const float* srow = (const float*)(ws + WS_SIM_OFF) + (size_t)t * 16;
        float4 v0 = *(const float4*)(srow + 0);
        float4 v1 = *(const float4*)(srow + 4);
        float4 v2 = *(const float4*)(srow + 8);
        float4 v3 = *(const float4*)(srow + 12);
        a16[0]=v0.x; a16[1]=v0.y; a16[2]=v0.z; a16[3]=v0.w;
        a16[4]=v1.x; a16[5]=v1.y; a16[6]=v1.z; a16[7]=v1.w;
        a16[8]=v2.x; a16[9]=v2.y; a16[10]=v2.z; a16[11]=v2.w;
        a16[12]=v3.x; a16[13]=v3.y; a16[14]=v3.z; a16[15]=v3.w;
        float m = a16[0];
        #pragma unroll
        for (int n = 1; n < 16; ++n) m = fmaxf(m, a16[n]);
        float den = 0.f;
        #pragma unroll
        for (int n = 0; n < 16; ++n) { a16[n] = expf(a16[n] - m); den += a16[n]; }
        float inv = 1.f / den;
        #pragma unroll
        for (int n = 0; n < 16; ++n) a16[n] *= inv;
    }
    #pragma unroll
    for (int n = 0; n < 16; ++n) {
        float p = a16[n];
        p += __shfl_xor(p, 1);  p += __shfl_xor(p, 2);
        p += __shfl_xor(p, 4);  p += __shfl_xor(p, 8);
        p += __shfl_xor(p, 16); p += __shfl_xor(p, 32);
        a16[n] = p;
    }
    if (l == 0) {
        #pragma unroll
        for (int n = 0; n < 16; ++n) Aw[w][n] = a16[n];
    }
    __syncthreads();
    if (t < 64) {
        int f = t >> 4, n = t & 15;
        Af[f][n] = Aw[4*f][n] + Aw[4*f+1][n] + Aw[4*f+2][n] + Aw[4*f+3][n];
    }
    __syncthreads();

    float sv[16];
    {
        const float* srow = (const float*)(ws + WS_S_OFF) + (size_t)t * 16;
        float4 v0 = *(const float4*)(srow + 0);
        float4 v1 = *(const float4*)(srow + 4);
        float4 v2 = *(const float4*)(srow + 8);
        float4 v3 = *(const float4*)(srow + 12);
        sv[0]=v0.x; sv[1]=v0.y; sv[2]=v0.z; sv[3]=v0.w;
        sv[4]=v1.x; sv[5]=v1.y; sv[6]=v1.z; sv[7]=v1.w;
        sv[8]=v2.x; sv[9]=v2.y; sv[10]=v2.z; sv[11]=v2.w;
        sv[12]=v3.x; sv[13]=v3.y; sv[14]=v3.z; sv[15]=v3.w;
    }
    float x[4];
    #pragma unroll
    for (int f = 0; f < 4; ++f) {
        float p = 0.f;
        #pragma unroll
        for (int n = 0; n < 16; ++n) p = fmaf(Af[f][n], sv[n], p);
        p *= (1.f / 16384.f);
        x[f] = (p >= 0.f) ? p : SLOPE * p;
    }

    float st[8];
    #pragma unroll
    for (int f = 0; f < 4; ++f) { st[f] = x[f]; st[4 + f] = x[f] * x[f]; }
    #pragma unroll
    for (int j = 0; j < 8; ++j) {
        float p = st[j];
        p += __shfl_xor(p, 1);  p += __shfl_xor(p, 2);
        p += __shfl_xor(p, 4);  p += __shfl_xor(p, 8);
        p += __shfl_xor(p, 16); p += __shfl_xor(p, 32);
        st[j] = p;
    }
    if (l == 0) {
        #pragma unroll
        for (int j = 0; j < 8; ++j) SWs[w][j] = st[j];
    }
    __syncthreads();
    if (t < 8) {
        float p = 0.f;
        #pragma unroll
        for (int ww = 0; ww < 16; ++ww) p += SWs[ww][t];
        FS[t] = p;
    }
    __syncthreads();
    if (t < 4) {
        float mean = FS[t] * (1.f / 1024.f);
        float var  = FS[4 + t] * (1.f / 1024.f) - mean * mean;
        float s = bn_w[t] / sqrtf(var + EPS);
        sc[t] = s;
        sh[t] = bn_b[t] - mean * s;
    }
    __syncthreads();

    float o0 = bo[0], o1 = bo[1];
    #pragma unroll
    for (int f = 0; f < 4; ++f) {
        float xh = x[f] * sc[f] + sh[f];
        o0 = fmaf(xh, Wo[f], o0);
        o1 = fmaf(xh, Wo[4 + f], o1);
    }
    *(float2*)(out + (size_t)t * 2) = make_float2(o0, o1);
}

// ---------------- launch ----------------
extern "C" void kernel_launch(void* const* d_in, const int* in_sizes, int n_in,
                              void* d_out, int out_size, void* d_ws, size_t ws_size,
                              hipStream_t stream) {
    const float* q_input  = (const float*)d_in[0];
    const float* kv_input = (const float*)d_in[1];
    const float* Wq   = (const float*)d_in[2];
    const float* bq   = (const float*)d_in[3];
    const float* Wkv  = (const float*)d_in[4];
    const float* bkv  = (const float*)d_in[5];
    const float* bn_w = (const float*)d_in[6];
    const float* bn_b = (const float*)d_in[7];
    const float* Wo   = (const float*)d_in[8];
    const float* bo   = (const float*)d_in[9];
    float* out = (float*)d_out;
    unsigned char* ws = (unsigned char*)d_ws;

    hipLaunchKernelGGL(prep_kernel, dim3((PREP_END + 255) / 256), dim3(256), 0, stream,
                       Wq, Wkv, bkv, ws);
    hipLaunchKernelGGL(gemm_qk_kernel, dim3(32, 16), dim3(256), 0, stream,
                       q_input, kv_input, ws);
    hipLaunchKernelGGL(sim_s_kernel, dim3(1024), dim3(256), 0, stream,
                       bq, bkv, kv_input, ws);
    hipLaunchKernelGGL(final_kernel, dim3(1), dim3(1024), 0, stream,
                       bn_w, bn_b, Wo, bo, ws, out);
}